// Round 16
// baseline (89.001 us; speedup 1.0000x reference)
//
#include <hip/hip_runtime.h>
#include <hip/hip_bf16.h>

// Problem: B=128, M=256, T=512, N=512
// D[k][n] = sum_t We2T[k][t]*X[t][n] per b; e[b,n] = sum_k tanh(D+g[b,k])*v[k];
// attn = softmax_n(e).  kblk=2 partials summed in softmax.
// R16: m201-geometry transplant — 8 waves, tile 128n x 256k, BK=64 ->
// 32 MFMA/wave/step (1240 SIMD-cyc > memory latency, finally hideable).

typedef _Float16 half8 __attribute__((ext_vector_type(8)));
typedef float floatx4 __attribute__((ext_vector_type(4)));

__device__ __forceinline__ float fast_tanh(float x) {
    float cx = fminf(15.0f, fmaxf(-15.0f, x));
    float e = __expf(2.0f * cx);
    return (e - 1.0f) * __fdividef(1.0f, e + 1.0f);
}

// ---------------- K0: Af slabs (A = We2^T f16, frag-linear) ----------------
// slab ts (32 t), chunk kg = k>>4 (0..31), lane l holds
// A[k=kg*16+(l&15)][t=ts*32+(l>>4)*8+j], j=0..7.  Elem ofs: ts*16384+kg*512+l*8.
__global__ __launch_bounds__(256) void k_prep_a(const float* __restrict__ We2,
                                                _Float16* __restrict__ Af) {
    __shared__ float w2[32][512];
    const int ts = blockIdx.x;
    for (int idx = threadIdx.x; idx < 32 * 512; idx += 256) {
        int tl = idx >> 9, k = idx & 511;
        w2[tl][k] = We2[(ts * 32 + tl) * 512 + k];
    }
    __syncthreads();
    for (int item = threadIdx.x; item < 32 * 64; item += 256) {
        int c = item >> 6, l = item & 63;
        int k  = c * 16 + (l & 15);
        int tl = (l >> 4) * 8;
        half8 h;
#pragma unroll
        for (int j = 0; j < 8; ++j) h[j] = (_Float16)w2[tl + j][k];
        *(half8*)&Af[(((size_t)ts * 32 + c) * 64 + l) * 8] = h;
    }
}

// ---------------- K1: g[b][k] = hc@We1 + be1 + be2 ----------------
__global__ __launch_bounds__(256) void k_hs(const float* __restrict__ hidden,
                                            const float* __restrict__ cell,
                                            const float* __restrict__ We1,
                                            const float* __restrict__ be1,
                                            const float* __restrict__ be2,
                                            float* __restrict__ g) {
    __shared__ __align__(16) float hcl[8][512];
    __shared__ float red[4][8][64];
    const int b0 = (blockIdx.x >> 3) << 3;
    const int k0 = (blockIdx.x & 7) << 6;
    for (int idx = threadIdx.x; idx < 8 * 512; idx += 256) {
        int bi = idx >> 9, j = idx & 511;
        hcl[bi][j] = (j < 256) ? hidden[(b0 + bi) * 256 + j]
                               : cell[(b0 + bi) * 256 + j - 256];
    }
    __syncthreads();
    const int kl = threadIdx.x & 63;
    const int jc = threadIdx.x >> 6;
    const int k  = k0 + kl;
    float acc[8] = {};
    for (int j = jc * 128; j < jc * 128 + 128; j += 4) {
        float w0 = We1[(j + 0) * 512 + k];
        float w1 = We1[(j + 1) * 512 + k];
        float w2 = We1[(j + 2) * 512 + k];
        float w3 = We1[(j + 3) * 512 + k];
#pragma unroll
        for (int bi = 0; bi < 8; ++bi) {
            float4 h = *(const float4*)&hcl[bi][j];
            acc[bi] += h.x * w0 + h.y * w1 + h.z * w2 + h.w * w3;
        }
    }
#pragma unroll
    for (int bi = 0; bi < 8; ++bi) red[jc][bi][kl] = acc[bi];
    __syncthreads();
    for (int idx = threadIdx.x; idx < 512; idx += 256) {
        int bi = idx >> 6, kk = idx & 63;
        float s = red[0][bi][kk] + red[1][bi][kk] + red[2][bi][kk] + red[3][bi][kk];
        int kg = k0 + kk;
        g[(b0 + bi) * 512 + kg] = s + be1[kg] + be2[kg];
    }
}

// ---------------- K2: fused GEMM, tile 128n x 256k, BK=64 ----------------
// grid 1024 = 128b x 4nt(128) x 2kblk, XCD chunk-swizzle.  512 thr = 8 waves
// (mw 2 x kw 4); wave = 64n x 64k -> 4mf x 4kf x 2ksub = 32 MFMA/step,
// 8 steps.  X: 2-deep reg sets -> cvt -> LDS dbuf 2x16KB frag-linear.
// W: frag-direct regs, 1-step dbuf from L2-hot Af.  Per-step VMEM queue
// [W(s+1):8][X(s+2):16] in order -> positional waits all counted.
__global__ __launch_bounds__(512, 2) void k_main(const float* __restrict__ X,
                                                 const _Float16* __restrict__ Af,
                                                 const float* __restrict__ g,
                                                 const float* __restrict__ vvec,
                                                 float* __restrict__ Ep) {
    __shared__ __align__(16) _Float16 Xb[2][8192];   // 2 x 16 KB
    const int tid  = threadIdx.x;
    const int lane = tid & 63;
    const int wv   = tid >> 6;        // 0..7
    const int l16  = lane & 15;
    const int lhi  = lane >> 4;       // 0..3
    const int mw   = wv >> 2;         // 0..1  (n-half of tile)
    const int kw   = wv & 3;          // 0..3  (k-quarter)
    const int logical = (blockIdx.x & 7) * 128 + (blockIdx.x >> 3);
    const int kblk = logical & 1;
    const int nt   = (logical >> 1) & 3;
    const int b    = logical >> 3;
    const int n0   = nt << 7;

    const float* Xg = X + (size_t)b * 262144 + n0;
    // W frag base: kg = kblk*16 + kw*4 + kf; elem ofs ts*16384 + kg*512 + l*8
    const _Float16* Ag = Af + (size_t)(kblk * 16 + kw * 4) * 512 + (size_t)lane * 8;

    // X staging map: xn = tid&127 (n), xob = tid>>7 (0..3).  Round r (0/1):
    // octet o = r*4+xob, t_loc = r*32 + xob*8 + j; ks = r; oo = xob.
    const int xn  = tid & 127;
    const int xob = tid >> 7;
    const float* Xt = Xg + (size_t)(xob * 8) * 512 + xn;
    const int wsl0 = (((xn >> 4) * 2 + 0) * 64 + (xn & 15) + (xob << 4)) * 8;
    const int wsl1 = (((xn >> 4) * 2 + 1) * 64 + (xn & 15) + (xob << 4)) * 8;

    float xsA[16], xsB[16];           // X(m) in set m&1
    half8 wfA[8], wfB[8];             // W(s) in set s&1

#define XLOAD(s_, arr_)                                                        \
    do { _Pragma("unroll")                                                     \
         for (int r = 0; r < 2; ++r)                                           \
             _Pragma("unroll")                                                 \
             for (int j = 0; j < 8; ++j)                                       \
                 arr_[r * 8 + j] =                                             \
                     Xt[(size_t)((s_) * 64 + r * 32 + j) * 512];               \
    } while (0)
#define XSTORE(s_, arr_)                                                       \
    do { half8 h0, h1;                                                         \
         _Pragma("unroll")                                                     \
         for (int j = 0; j < 8; ++j) { h0[j] = (_Float16)arr_[j];              \
                                       h1[j] = (_Float16)arr_[8 + j]; }        \
         *(half8*)&Xb[(s_) & 1][wsl0] = h0;                                    \
         *(half8*)&Xb[(s_) & 1][wsl1] = h1;                                    \
    } while (0)
#define WLOAD(s_, arr_)                                                        \
    do { _Pragma("unroll")                                                     \
         for (int ks = 0; ks < 2; ++ks)                                        \
             _Pragma("unroll")                                                 \
             for (int kf = 0; kf < 4; ++kf)                                    \
                 arr_[ks * 4 + kf] = *(const half8*)                           \
                     (Ag + (size_t)((s_) * 2 + ks) * 16384 + kf * 512);        \
    } while (0)

    // ---- prologue: X(0),X(1),W(0) in flight; X(0) -> Xb[0]
    XLOAD(0, xsA);
    XLOAD(1, xsB);
    WLOAD(0, wfA);
    XSTORE(0, xsA);                   // waits X(0) only (X1,W0 newer)
    asm volatile("s_waitcnt lgkmcnt(0)" ::: "memory");
    __builtin_amdgcn_sched_barrier(0);
    __builtin_amdgcn_s_barrier();
    __builtin_amdgcn_sched_barrier(0);

    floatx4 acc[4][4];
#pragma unroll
    for (int a = 0; a < 4; ++a)
#pragma unroll
        for (int c = 0; c < 4; ++c) acc[a][c] = (floatx4){0.f, 0.f, 0.f, 0.f};

#pragma unroll
    for (int s = 0; s < 8; ++s) {
        const int cur = s & 1;
        // 1. issue W(s+1) into spare set
        if (s + 1 < 8) {
            if ((s & 1) == 0) WLOAD(s + 1, wfB);
            else              WLOAD(s + 1, wfA);
        }
        // 2. issue X(s+2) into set s&1 (its X(s) content was cvt'd last step)
        if (s + 2 < 8) {
            if ((s & 1) == 0) XLOAD(s + 2, xsA);
            else              XLOAD(s + 2, xsB);
        }
        __builtin_amdgcn_sched_barrier(0);
        // 3. cvt + write X(s+1) from set (s+1)&1 -> Xb[cur^1]
        //    (positional wait vmcnt(24): W(s+1)/X(s+2) stay in flight)
        if (s + 1 < 8) {
            if ((s & 1) == 0) XSTORE(s + 1, xsB);
            else              XSTORE(s + 1, xsA);
        }
        __builtin_amdgcn_sched_barrier(0);
        // 4. frag reads + 32 MFMA (W regs prefetched last step)
        __builtin_amdgcn_s_setprio(1);
#pragma unroll
        for (int mf = 0; mf < 4; ++mf) {
#pragma unroll
            for (int ks = 0; ks < 2; ++ks) {
                half8 xf = *(const half8*)
                    &Xb[cur][((mw * 4 + mf) * 2 + ks) * 512 + lane * 8];
                if ((s & 1) == 0) {
#pragma unroll
                    for (int kf = 0; kf < 4; ++kf)
                        acc[mf][kf] = __builtin_amdgcn_mfma_f32_16x16x32_f16(
                            wfA[ks * 4 + kf], xf, acc[mf][kf], 0, 0, 0);
                } else {
#pragma unroll
                    for (int kf = 0; kf < 4; ++kf)
                        acc[mf][kf] = __builtin_amdgcn_mfma_f32_16x16x32_f16(
                            wfB[ks * 4 + kf], xf, acc[mf][kf], 0, 0, 0);
                }
            }
        }
        __builtin_amdgcn_s_setprio(0);
        // 5. LDS drain + barrier (no vmcnt: prefetches stay in flight)
        asm volatile("s_waitcnt lgkmcnt(0)" ::: "memory");
        __builtin_amdgcn_sched_barrier(0);
        __builtin_amdgcn_s_barrier();
        __builtin_amdgcn_sched_barrier(0);
    }
#undef XLOAD
#undef XSTORE
#undef WLOAD

    // ---- fused epilogue: s[n] = sum_{k in wave 64-slice} tanh(acc+g)*v
    // D layout: row k = lhi*4+reg (within kf 16-group), col n = l16
    const float* gb = g + b * 512;
    float sacc[4] = {0.f, 0.f, 0.f, 0.f};   // per mf
#pragma unroll
    for (int kf = 0; kf < 4; ++kf) {
        const int kb = kblk * 256 + kw * 64 + kf * 16 + lhi * 4;
        float g0 = gb[kb + 0], g1 = gb[kb + 1], g2 = gb[kb + 2], g3 = gb[kb + 3];
        float v0 = vvec[kb + 0], v1 = vvec[kb + 1], v2 = vvec[kb + 2], v3 = vvec[kb + 3];
#pragma unroll
        for (int mf = 0; mf < 4; ++mf) {
            sacc[mf] += fast_tanh(acc[mf][kf][0] + g0) * v0;
            sacc[mf] += fast_tanh(acc[mf][kf][1] + g1) * v1;
            sacc[mf] += fast_tanh(acc[mf][kf][2] + g2) * v2;
            sacc[mf] += fast_tanh(acc[mf][kf][3] + g3) * v3;
        }
    }
#pragma unroll
    for (int mf = 0; mf < 4; ++mf) {
        sacc[mf] += __shfl_xor(sacc[mf], 16);
        sacc[mf] += __shfl_xor(sacc[mf], 32);
    }
    __syncthreads();                 // loop drained -> overlay on Xb
    float* ered = (float*)&Xb[0][0]; // [4 kw][128 n]
    if (lane < 16) {
#pragma unroll
        for (int mf = 0; mf < 4; ++mf)
            ered[kw * 128 + mw * 64 + mf * 16 + l16] = sacc[mf];
    }
    __syncthreads();
    if (tid < 128) {
        float e = ered[tid] + ered[128 + tid] + ered[256 + tid] + ered[384 + tid];
        Ep[(size_t)kblk * 65536 + b * 512 + n0 + tid] = e;
    }
}

// ---------------- K3: softmax over n (512), summing 2 k-partials ------------
__global__ __launch_bounds__(256) void k_softmax(const float* __restrict__ Ep,
                                                 float* __restrict__ out) {
    __shared__ float rmax[4], rsum[4];
    const int b = blockIdx.x;
    const int tid = threadIdx.x;
    const float* E0 = Ep;
    const float* E1 = Ep + 65536;
    float e0 = E0[b * 512 + tid] + E1[b * 512 + tid];
    float e1 = E0[b * 512 + 256 + tid] + E1[b * 512 + 256 + tid];
    float m = fmaxf(e0, e1);
    for (int o = 32; o > 0; o >>= 1) m = fmaxf(m, __shfl_xor(m, o));
    if ((tid & 63) == 0) rmax[tid >> 6] = m;
    __syncthreads();
    m = fmaxf(fmaxf(rmax[0], rmax[1]), fmaxf(rmax[2], rmax[3]));
    float p0 = __expf(e0 - m), p1 = __expf(e1 - m);
    float ss = p0 + p1;
    for (int o = 32; o > 0; o >>= 1) ss += __shfl_xor(ss, o);
    if ((tid & 63) == 0) rsum[tid >> 6] = ss;
    __syncthreads();
    ss = rsum[0] + rsum[1] + rsum[2] + rsum[3];
    float inv = __fdividef(1.0f, ss);
    out[b * 512 + tid] = p0 * inv;
    out[b * 512 + 256 + tid] = p1 * inv;
}

extern "C" void kernel_launch(void* const* d_in, const int* in_sizes, int n_in,
                              void* d_out, int out_size, void* d_ws, size_t ws_size,
                              hipStream_t stream) {
    const float* hidden = (const float*)d_in[0];
    const float* cell   = (const float*)d_in[1];
    const float* X      = (const float*)d_in[2];
    const float* We1    = (const float*)d_in[3];
    const float* be1    = (const float*)d_in[4];
    const float* We2    = (const float*)d_in[5];
    const float* be2    = (const float*)d_in[6];
    const float* v      = (const float*)d_in[7];
    float* out = (float*)d_out;

    char* ws = (char*)d_ws;
    _Float16* Af = (_Float16*)ws;                        // 512*512*2   = 524288 B
    float* g     = (float*)(ws + 524288);                // 128*512*4   = 262144 B
    float* Ep    = (float*)(ws + 786432);                // 2*128*512*4 = 524288 B

    k_prep_a<<<16, 256, 0, stream>>>(We2, Af);
    k_hs<<<128, 256, 0, stream>>>(hidden, cell, We1, be1, be2, g);
    k_main<<<1024, 512, 0, stream>>>(X, Af, g, v, Ep);
    k_softmax<<<128, 256, 0, stream>>>(Ep, out);
}

// Round 17
// 85.510 us; speedup vs baseline: 1.0408x; 1.0408x over previous
//
#include <hip/hip_runtime.h>
#include <hip/hip_bf16.h>

// Problem: B=128, M=256, T=512, N=512
// e[b,n] = sum_k tanh( (sum_t We2T[k][t]*X[b,t,n]) + g[b,k] ) * v[k]; softmax_n.
// R17: traffic-minimal. Block = (b, 128n); FULL X strip [512t][128n] f16
// resident in LDS (128 KB, staged once). k=512 unsplit -> X read once total
// (134 MB) + A 256 MB L2-hot = 390 MB serviced (R16: 524+). Main loop:
// barrier-free, no LDS writes, no cvt — only A reg-prefetch + ds_read + MFMA.

typedef _Float16 half8 __attribute__((ext_vector_type(8)));
typedef float floatx4 __attribute__((ext_vector_type(4)));

__device__ __forceinline__ float fast_tanh(float x) {
    float cx = fminf(15.0f, fmaxf(-15.0f, x));
    float e = __expf(2.0f * cx);
    return (e - 1.0f) * __fdividef(1.0f, e + 1.0f);
}

// ---------------- K0: Af slabs (A = We2^T f16, frag-linear) ----------------
// slab ts (32 t), chunk kg (0..31), lane l holds
// A[k=kg*16+(l&15)][t=ts*32+(l>>4)*8+j], j=0..7.  Elem ofs: ts*16384+kg*512+l*8.
__global__ __launch_bounds__(256) void k_prep_a(const float* __restrict__ We2,
                                                _Float16* __restrict__ Af) {
    __shared__ float w2[32][512];
    const int ts = blockIdx.x;
    for (int idx = threadIdx.x; idx < 32 * 512; idx += 256) {
        int tl = idx >> 9, k = idx & 511;
        w2[tl][k] = We2[(ts * 32 + tl) * 512 + k];
    }
    __syncthreads();
    for (int item = threadIdx.x; item < 32 * 64; item += 256) {
        int c = item >> 6, l = item & 63;
        int k  = c * 16 + (l & 15);
        int tl = (l >> 4) * 8;
        half8 h;
#pragma unroll
        for (int j = 0; j < 8; ++j) h[j] = (_Float16)w2[tl + j][k];
        *(half8*)&Af[(((size_t)ts * 32 + c) * 64 + l) * 8] = h;
    }
}

// ---------------- K1: g[b][k] = hc@We1 + be1 + be2 ----------------
__global__ __launch_bounds__(256) void k_hs(const float* __restrict__ hidden,
                                            const float* __restrict__ cell,
                                            const float* __restrict__ We1,
                                            const float* __restrict__ be1,
                                            const float* __restrict__ be2,
                                            float* __restrict__ g) {
    __shared__ __align__(16) float hcl[8][512];
    __shared__ float red[4][8][64];
    const int b0 = (blockIdx.x >> 3) << 3;
    const int k0 = (blockIdx.x & 7) << 6;
    for (int idx = threadIdx.x; idx < 8 * 512; idx += 256) {
        int bi = idx >> 9, j = idx & 511;
        hcl[bi][j] = (j < 256) ? hidden[(b0 + bi) * 256 + j]
                               : cell[(b0 + bi) * 256 + j - 256];
    }
    __syncthreads();
    const int kl = threadIdx.x & 63;
    const int jc = threadIdx.x >> 6;
    const int k  = k0 + kl;
    float acc[8] = {};
    for (int j = jc * 128; j < jc * 128 + 128; j += 4) {
        float w0 = We1[(j + 0) * 512 + k];
        float w1 = We1[(j + 1) * 512 + k];
        float w2 = We1[(j + 2) * 512 + k];
        float w3 = We1[(j + 3) * 512 + k];
#pragma unroll
        for (int bi = 0; bi < 8; ++bi) {
            float4 h = *(const float4*)&hcl[bi][j];
            acc[bi] += h.x * w0 + h.y * w1 + h.z * w2 + h.w * w3;
        }
    }
#pragma unroll
    for (int bi = 0; bi < 8; ++bi) red[jc][bi][kl] = acc[bi];
    __syncthreads();
    for (int idx = threadIdx.x; idx < 512; idx += 256) {
        int bi = idx >> 6, kk = idx & 63;
        float s = red[0][bi][kk] + red[1][bi][kk] + red[2][bi][kk] + red[3][bi][kk];
        int kg = k0 + kk;
        g[(b0 + bi) * 512 + kg] = s + be1[kg] + be2[kg];
    }
}

// ---------------- K2: X-resident fused GEMM, k=512 in-block ----------------
// grid 512 = 128b x 4nt(128n), XCD-swizzled; 1 block/CU, 2 rounds.
// 512 thr = 8 waves (wn 2 x wk 4); wave = 64n(wn half of 128? -> wn*64..)
//   wave tile: k [wk*128,+128) x n [wn*64..+64)  -> 8kf x 4nf = 32 MFMA/step.
// Phase 1: stage X strip [512t][128n] f32->f16 into 128 KB LDS (frag-linear,
// 2-deep reg pipeline).  Phase 2 (after ONE barrier): 16 steps, barrier-free:
// A(s) regs (prefetched 1 step ahead, 8x coalesced b128 from L2-hot Af) +
// 4 conflict-free ds_read_b128 + 32 MFMA.  Named A-sets bound lookahead (WAR).
__global__ __launch_bounds__(512, 1) void k_main(const float* __restrict__ X,
                                                 const _Float16* __restrict__ Af,
                                                 const float* __restrict__ g,
                                                 const float* __restrict__ vvec,
                                                 float* __restrict__ E) {
    __shared__ __align__(16) _Float16 Xb[65536];   // 128 KB
    const int tid  = threadIdx.x;
    const int lane = tid & 63;
    const int wv   = tid >> 6;        // 0..7
    const int l16  = lane & 15;
    const int lhi  = lane >> 4;       // 0..3
    const int wn   = wv >> 2;         // 0..1
    const int wk   = wv & 3;          // 0..3
    const int logical = (blockIdx.x & 7) * 64 + (blockIdx.x >> 3);
    const int nt   = logical & 3;
    const int b    = logical >> 2;
    const int n0   = nt << 7;

    const float* Xg = X + (size_t)b * 262144 + n0;
    // A frag base: wave wk covers chunks kg = wk*8 + kf
    const _Float16* Ag = Af + (size_t)(wk * 8) * 512 + (size_t)lane * 8;

    // ---- Phase 1: stage X strip (once).  xn = n, xq = t-octet group.
    {
        const int xn = tid & 127;
        const int xq = tid >> 7;      // 0..3
        const float* Xt = Xg + (size_t)(xq * 8) * 512 + xn;
        const int slotb = ((xn >> 4) * 64 + (xq << 4) + (xn & 15)) * 8;
        float xsA[8], xsB[8];
#define XSLOAD(s_, arr_)                                                       \
        do { _Pragma("unroll")                                                 \
             for (int j = 0; j < 8; ++j)                                       \
                 arr_[j] = Xt[(size_t)((s_) * 32 + j) * 512];                  \
        } while (0)
#define XSSTORE(s_, arr_)                                                      \
        do { half8 h;                                                          \
             _Pragma("unroll")                                                 \
             for (int j = 0; j < 8; ++j) h[j] = (_Float16)arr_[j];             \
             *(half8*)&Xb[(s_) * 4096 + slotb] = h;                            \
        } while (0)
        XSLOAD(0, xsA);
#pragma unroll
        for (int ts = 0; ts < 16; ++ts) {
            if (ts + 1 < 16) {
                if (((ts + 1) & 1) == 0) XSLOAD(ts + 1, xsA);
                else                     XSLOAD(ts + 1, xsB);
            }
            if ((ts & 1) == 0) XSSTORE(ts, xsA);
            else               XSSTORE(ts, xsB);
        }
#undef XSLOAD
#undef XSSTORE
    }
    __syncthreads();     // the ONLY pre-epilogue barrier

    floatx4 acc[8][4];
#pragma unroll
    for (int a = 0; a < 8; ++a)
#pragma unroll
        for (int c = 0; c < 4; ++c) acc[a][c] = (floatx4){0.f, 0.f, 0.f, 0.f};

    half8 afA[8], afB[8];
#define ALOAD(s_, arr_)                                                        \
    do { _Pragma("unroll")                                                     \
         for (int kf = 0; kf < 8; ++kf)                                        \
             arr_[kf] = *(const half8*)(Ag + (size_t)(s_) * 16384 +            \
                                        (size_t)kf * 512);                     \
    } while (0)
    ALOAD(0, afA);

#pragma unroll
    for (int s = 0; s < 16; ++s) {
        // 1. prefetch A(s+1) into spare named set (WAR bounds lookahead)
        if (s + 1 < 16) {
            if ((s & 1) == 0) ALOAD(s + 1, afB);
            else              ALOAD(s + 1, afA);
        }
        __builtin_amdgcn_sched_barrier(0);
        // 2. X fragments: 4 x conflict-free ds_read_b128
        half8 xf[4];
#pragma unroll
        for (int nf = 0; nf < 4; ++nf)
            xf[nf] = *(const half8*)
                &Xb[((s * 8 + wn * 4 + nf) * 64 + lane) * 8];
        // 3. 32 MFMA with A(s) prefetched last step (positional vmcnt leaves
        //    A(s+1) in flight)
        __builtin_amdgcn_s_setprio(1);
        if ((s & 1) == 0) {
#pragma unroll
            for (int kf = 0; kf < 8; ++kf)
#pragma unroll
                for (int nf = 0; nf < 4; ++nf)
                    acc[kf][nf] = __builtin_amdgcn_mfma_f32_16x16x32_f16(
                        afA[kf], xf[nf], acc[kf][nf], 0, 0, 0);
        } else {
#pragma unroll
            for (int kf = 0; kf < 8; ++kf)
#pragma unroll
                for (int nf = 0; nf < 4; ++nf)
                    acc[kf][nf] = __builtin_amdgcn_mfma_f32_16x16x32_f16(
                        afB[kf], xf[nf], acc[kf][nf], 0, 0, 0);
        }
        __builtin_amdgcn_s_setprio(0);
        __builtin_amdgcn_sched_barrier(0);
    }
#undef ALOAD

    // ---- fused epilogue: e[n] = sum_k tanh(acc + g[k]) * v[k]
    // D layout: row k = wk*128 + kf*16 + lhi*4 + reg, col n = wn*64+nf*16+l16
    const float* gb = g + b * 512;
    float sacc[4] = {0.f, 0.f, 0.f, 0.f};
#pragma unroll
    for (int kf = 0; kf < 8; ++kf) {
        const int kb = wk * 128 + kf * 16 + lhi * 4;
        float g0 = gb[kb + 0], g1 = gb[kb + 1], g2 = gb[kb + 2], g3 = gb[kb + 3];
        float v0 = vvec[kb + 0], v1 = vvec[kb + 1], v2 = vvec[kb + 2], v3 = vvec[kb + 3];
#pragma unroll
        for (int nf = 0; nf < 4; ++nf) {
            sacc[nf] += fast_tanh(acc[kf][nf][0] + g0) * v0;
            sacc[nf] += fast_tanh(acc[kf][nf][1] + g1) * v1;
            sacc[nf] += fast_tanh(acc[kf][nf][2] + g2) * v2;
            sacc[nf] += fast_tanh(acc[kf][nf][3] + g3) * v3;
        }
    }
#pragma unroll
    for (int nf = 0; nf < 4; ++nf) {
        sacc[nf] += __shfl_xor(sacc[nf], 16);
        sacc[nf] += __shfl_xor(sacc[nf], 32);
    }
    __syncthreads();                 // X reads done -> overlay on Xb
    float* ered = (float*)&Xb[0];    // [4 wk][128 n]
    if (lane < 16) {
#pragma unroll
        for (int nf = 0; nf < 4; ++nf)
            ered[wk * 128 + wn * 64 + nf * 16 + l16] = sacc[nf];
    }
    __syncthreads();
    if (tid < 128) {
        float e = ered[tid] + ered[128 + tid] + ered[256 + tid] + ered[384 + tid];
        E[b * 512 + n0 + tid] = e;
    }
}

// ---------------- K3: softmax over n (512) per batch row ----------------
__global__ __launch_bounds__(256) void k_softmax(const float* __restrict__ E,
                                                 float* __restrict__ out) {
    __shared__ float rmax[4], rsum[4];
    const int b = blockIdx.x;
    const int tid = threadIdx.x;
    float e0 = E[b * 512 + tid];
    float e1 = E[b * 512 + 256 + tid];
    float m = fmaxf(e0, e1);
    for (int o = 32; o > 0; o >>= 1) m = fmaxf(m, __shfl_xor(m, o));
    if ((tid & 63) == 0) rmax[tid >> 6] = m;
    __syncthreads();
    m = fmaxf(fmaxf(rmax[0], rmax[1]), fmaxf(rmax[2], rmax[3]));
    float p0 = __expf(e0 - m), p1 = __expf(e1 - m);
    float ss = p0 + p1;
    for (int o = 32; o > 0; o >>= 1) ss += __shfl_xor(ss, o);
    if ((tid & 63) == 0) rsum[tid >> 6] = ss;
    __syncthreads();
    ss = rsum[0] + rsum[1] + rsum[2] + rsum[3];
    float inv = __fdividef(1.0f, ss);
    out[b * 512 + tid] = p0 * inv;
    out[b * 512 + 256 + tid] = p1 * inv;
}

extern "C" void kernel_launch(void* const* d_in, const int* in_sizes, int n_in,
                              void* d_out, int out_size, void* d_ws, size_t ws_size,
                              hipStream_t stream) {
    const float* hidden = (const float*)d_in[0];
    const float* cell   = (const float*)d_in[1];
    const float* X      = (const float*)d_in[2];
    const float* We1    = (const float*)d_in[3];
    const float* be1    = (const float*)d_in[4];
    const float* We2    = (const float*)d_in[5];
    const float* be2    = (const float*)d_in[6];
    const float* v      = (const float*)d_in[7];
    float* out = (float*)d_out;

    char* ws = (char*)d_ws;
    _Float16* Af = (_Float16*)ws;                        // 512*512*2 = 524288 B
    float* g     = (float*)(ws + 524288);                // 128*512*4 = 262144 B
    float* E     = (float*)(ws + 786432);                // 128*512*4 = 262144 B

    k_prep_a<<<16, 256, 0, stream>>>(We2, Af);
    k_hs<<<128, 256, 0, stream>>>(hidden, cell, We1, be1, be2, g);
    k_main<<<512, 512, 0, stream>>>(X, Af, g, v, E);
    k_softmax<<<128, 256, 0, stream>>>(E, out);
}